// Round 12
// baseline (236.365 us; speedup 1.0000x reference)
//
#include <hip/hip_runtime.h>
#include <cfloat>
#include <cstddef>

// VQ-VAE vector quantizer, MI355X / gfx950.
// z: (32, 64, 32, 32) f32 BCHW; embedding: (1024, 64) f32.
// Outputs concatenated f32: loss[1], z_q(BCHW)[2097152], perplexity[1],
// min_encodings[32768*1024], min_encoding_indices(as float)[32768].
//
// Structure history (measured):
//   R1-R6: delivery-path search. Scalar (s_load) streaming of the codebook
//     is the only replication-free broadcast; everything else pays 64x.
//   R7-R11: scan/epi split experiments. Key measurements:
//     - R9 (best total, 211us): TPB 256, launch_bounds(256,5), 4 waves x
//       64-code chunks, no barriers, zero-fill interleaved -> scan ~70-75us.
//     - R10/R11 (93/95us scan): asm v_pk_fma and named-locals changed
//       NOTHING (VALU-busy time identical ~43us).
//   ARITHMETIC that explains R10/R11: peak vector FP32 = 157.3 TF =
//     256 FLOP/cyc/CU. v_pk_fma_f32 therefore runs 4cyc/wave64 (two pipe
//     passes) -- packing halves instruction count, NOT FLOP time. Scan
//     FLOP floor = 4.3 GFLOP / 157.3 TF ~= 27us; measured VALU time 43us
//     (1.6x floor, rest is scalar-latency stall at ~55%).
//   R12 (this): stop shaving the floor; remove overhead instead.
//     Resurrect R9's best-measured scan geometry VERBATIM and fuse the
//     epilogue into the same kernel: in-block LDS combine (4 waves cover
//     all 1024 codes) -> scatter/idx/hist -> R1's loss tree, all behind
//     one __syncthreads. Deletes the epi kernel (~25us), the candidate
//     stash traffic, and one launch gap.
//
// Numerics (must match the absmax-0.0 lineage bit-for-bit):
//   dot: 4 fp32 fma chains m=c%4 over k ascending, final (a0+a1)+(a2+a3);
//     v2f elementwise_fma packs chains (a0,a1),(a2,a3) -- identical
//     per-element rounding, proven exact R2-R11 (R9 ran THIS exact loop).
//   e2/z2: sequential double accumulation (ch ascending), rounded once
//     (e2 in a pre-kernel, proven R5-R11; z2 from row regs, c ascending).
//   d = (z2f + e2f) - 2.0f*dot (two fp32 roundings at magnitude ~64).
//   argmin: wave q scans [256q, 256q+256) ascending with strict <
//     (first index); in-block combine over w = 0..3 ascending (ascending
//     code ranges, strict <) -> exact np.argmin first-index semantics.
//   loss: fused tail reproduces R1's partial[512] tree verbatim (wave q
//     handles classes {q, q+4}, chains c = cls + 8i ascending, shfl_down
//     butterfly, ascending-class sums); vq_final unchanged.

#define NROWS 32768
#define NE    1024
#define EDIM  64
#define TPB   256
#define GRID  512             // one block per 64 rows
#define NPART 512

#define OFF_LOSS ((size_t)0)
#define OFF_ZQ   ((size_t)1)
#define OFF_PERP ((size_t)2097153)
#define OFF_OH   ((size_t)2097154)
#define OFF_IDX  ((size_t)35651586)

typedef float v2f __attribute__((ext_vector_type(2)));

// ws layout (bytes): [0,4096) int hist[1024]; [4096,6144) float partial[512];
//                    [8192,12288) float e2buf[1024]

__global__ __launch_bounds__(128) void vq_e2(const float* __restrict__ emb,
                                             float* __restrict__ e2buf,
                                             int* __restrict__ hist) {
    int j = blockIdx.x * 128 + threadIdx.x;          // grid 8x128 = 1024
    hist[j] = 0;                                     // replaces hipMemsetAsync
    const float* e = emb + ((size_t)j << 6);
    double s = 0.0;
#pragma unroll
    for (int c = 0; c < EDIM; ++c) { float v = e[c]; s += (double)v * (double)v; }
    e2buf[j] = (float)s;
}

__global__ __launch_bounds__(TPB, 5) void vq_fused(const float* __restrict__ z,
                                                   const float* __restrict__ emb,
                                                   const float* __restrict__ e2buf,
                                                   int* __restrict__ hist,
                                                   float* __restrict__ partial,
                                                   float* __restrict__ out) {
    const int t    = threadIdx.x;
    const int lane = t & 63;
    const int q    = t >> 6;                 // wave 0..3
    const int r0   = blockIdx.x << 6;        // 64 rows per block
    // readfirstlane: provably wave-uniform -> codebook loads stay SCALAR
    // (s_load). Without it divergence analysis sees q as divergent and
    // emits vector loads (R2's 64x replication disaster).
    const int qu   = __builtin_amdgcn_readfirstlane(q);

    const int row  = r0 + lane;              // lane owns this row
    const int b    = row >> 10;
    const int m    = row & 1023;
    const size_t zbase = (size_t)b * 65536 + (size_t)m;

    __shared__ float s_wd[4][64];
    __shared__ int   s_wj[4][64];
    __shared__ int   s_idx[64];
    __shared__ float s_l[8];

    // ---- this lane's z row (64 ch, stride 1024) + ||z||^2 -----------------
    v2f zp[32];
    double sd = 0.0;
#pragma unroll
    for (int n = 0; n < 32; ++n) {
        float x = z[zbase + (size_t)(2 * n) * 1024];
        float y = z[zbase + (size_t)(2 * n + 1) * 1024];
        zp[n] = (v2f){x, y};
        sd += (double)x * (double)x;         // c ascending: 2n then 2n+1
        sd += (double)y * (double)y;
    }
    const float z2f = (float)sd;             // consumes loads -> vmcnt drains

    // one-hot zero-fill: rows [r0,+64) x ALL 1024 cols = 256 KB = 32768
    // float2. Issued inside the scan loop (1 store per 2 codes, 128/thread):
    // vmem queue stays shallow, stores drain under the compute, and the
    // __syncthreads before the scatter drains vmcnt(0) -> zeros visible
    // before the 1.0f lands (R1-lineage proven ordering).
    float* ohb = out + OFF_OH + (size_t)r0 * 1024;   // 8B-aligned

    // ---- scan this wave's 256 codes via scalar stream (R9 verbatim) -------
    // 20 waves/CU (5 blocks x 4 waves): per-wave duty ~33% (VALU ~140cyc vs
    // ~300cyc exposed SMEM latency, no SGPR double-buffer possible) x5 ->
    // near-saturated. No barriers, no stagger.
    const int jf = qu << 8;
    float bestd = FLT_MAX;
    int   bestj = 0;
    for (int jj = 0; jj < 256; ++jj) {
        if (!(jj & 1)) {
            int i  = t + (jj >> 1) * TPB;    // 0..32767
            int r  = i >> 9;                 // 0..63
            int c2 = i & 511;                // float2 column within 1024 cols
            *(float2*)(ohb + (size_t)r * 1024 + 2 * c2) = make_float2(0.f, 0.f);
        }
        const int j = jf + jj;
        const float4* ep = (const float4*)(emb + ((size_t)j << 6));
        const float e2f = e2buf[j];          // s_load (uniform)
        float4 e[16];
#pragma unroll
        for (int k = 0; k < 16; ++k) e[k] = ep[k];   // s_load_dwordx16 x4
        v2f a01 = {0.f, 0.f}, a23 = {0.f, 0.f};
#pragma unroll
        for (int k = 0; k < 16; ++k) {
            v2f exy = {e[k].x, e[k].y};
            v2f ezw = {e[k].z, e[k].w};
            a01 = __builtin_elementwise_fma(exy, zp[2 * k],     a01);
            a23 = __builtin_elementwise_fma(ezw, zp[2 * k + 1], a23);
        }
        float dot = (a01.x + a01.y) + (a23.x + a23.y);
        float d   = (z2f + e2f) - 2.0f * dot;
        if (d < bestd) { bestd = d; bestj = j; }     // ascending: first index
    }

    // ---- in-block combine over 4 waves (ascending j ranges, strict <) ----
    s_wd[q][lane] = bestd;
    s_wj[q][lane] = bestj;
    __syncthreads();   // also drains vmcnt(0): zero-fill globally visible
    if (t < 64) {
        float bd = s_wd[0][t];
        int   bj = s_wj[0][t];
#pragma unroll
        for (int w = 1; w < 4; ++w) {
            float dw = s_wd[w][t];
            if (dw < bd) { bd = dw; bj = s_wj[w][t]; }  // strict <: first idx
        }
        s_idx[t] = bj;
        const int rr = r0 + t;
        out[OFF_IDX + rr] = (float)bj;                       // index as float
        out[OFF_OH + (size_t)rr * 1024 + bj] = 1.0f;         // one-hot scatter
        atomicAdd(&hist[bj], 1);
    }
    __syncthreads();

    // ---- z_q (straight-through) + loss partial: R1's tree verbatim -------
    // wave q handles classes {q, q+4}; chains c = cls + 8i (i ascending),
    // shfl_down butterfly, s_l[8] summed ascending -> partial[512]
    // bit-identical to the R1 lineage; vq_final unchanged.
    {
        const int    jjx = s_idx[lane];
        const float* er  = emb + ((size_t)jjx << 6);
        float* zq = out + OFF_ZQ + zbase;
#pragma unroll
        for (int p = 0; p < 2; ++p) {
            const int cls = q + 4 * p;
            float ls = 0.f;
#pragma unroll
            for (int i = 0; i < 8; ++i) {
                int c = cls + 8 * i;
                float zc   = z[zbase + (size_t)c * 1024];     // coalesced, L2
                float ev   = er[c];                           // gather (L2)
                float diff = ev - zc;
                zq[(size_t)c * 1024] = zc + diff;             // zp + (z_q-zp)
                ls = fmaf(diff, diff, ls);
            }
#pragma unroll
            for (int off = 32; off >= 1; off >>= 1) ls += __shfl_down(ls, off);
            if (lane == 0) s_l[cls] = ls;
        }
        __syncthreads();
        if (t == 0) {
            float l = 0.f;
#pragma unroll
            for (int c = 0; c < 8; ++c) l += s_l[c];          // ascending
            partial[blockIdx.x] = l;
        }
    }
}

__global__ __launch_bounds__(1024) void vq_final(const int* __restrict__ hist,
                                                 const float* __restrict__ partial,
                                                 float* __restrict__ out) {
    int t = threadIdx.x;
    float p    = (float)hist[t] * (1.0f / 32768.0f);
    float term = p * logf(p + 1e-10f);
    float lp   = (t < NPART) ? partial[t] : 0.f;
#pragma unroll
    for (int off = 32; off >= 1; off >>= 1) {
        term += __shfl_down(term, off);
        lp   += __shfl_down(lp, off);
    }
    __shared__ float st[16], sl[16];
    int w = t >> 6, ln = t & 63;
    if (ln == 0) { st[w] = term; sl[w] = lp; }
    __syncthreads();
    if (t == 0) {
        float s = 0.f, l = 0.f;
#pragma unroll
        for (int i = 0; i < 16; ++i) { s += st[i]; l += sl[i]; }
        out[OFF_LOSS] = 1.25f * l * (1.0f / 2097152.0f);  // (1+beta)*mean
        out[OFF_PERP] = expf(-s);
    }
}

extern "C" void kernel_launch(void* const* d_in, const int* in_sizes, int n_in,
                              void* d_out, int out_size, void* d_ws, size_t ws_size,
                              hipStream_t stream) {
    const float* z   = (const float*)d_in[0];
    const float* emb = (const float*)d_in[1];
    float* out     = (float*)d_out;
    int*   hist    = (int*)d_ws;
    float* partial = (float*)((char*)d_ws + 4096);
    float* e2buf   = (float*)((char*)d_ws + 8192);

    vq_e2<<<8, 128, 0, stream>>>(emb, e2buf, hist);
    vq_fused<<<GRID, TPB, 0, stream>>>(z, emb, e2buf, hist, partial, out);
    vq_final<<<1, 1024, 0, stream>>>(hist, partial, out);
}